// Round 2
// baseline (1085.176 us; speedup 1.0000x reference)
//
#include <hip/hip_runtime.h>
#include <hip/hip_bf16.h>

// Problem constants (from reference)
#define NPTS   160000    // B*P = 4*40000
#define DIM    128
#define HID    512
#define KK2    49        // 7x7
#define DEPTH  2

typedef __attribute__((ext_vector_type(8))) short bf16x8;
typedef __attribute__((ext_vector_type(4))) float f32x4;

static __device__ __forceinline__ ushort f2bf(float f) {
    unsigned u = __float_as_uint(f);
    return (ushort)((u + 0x7fffu + ((u >> 16) & 1u)) >> 16);
}
static __device__ __forceinline__ float lo16(unsigned u) { return __uint_as_float(u << 16); }
static __device__ __forceinline__ float hi16(unsigned u) { return __uint_as_float(u & 0xffff0000u); }

// ---------------------------------------------------------------------------
// fp32 -> bf16 cast (4 elems/thread), exact-size grid
// ---------------------------------------------------------------------------
__global__ __launch_bounds__(256) void cast_bf16_kernel(
    const float* __restrict__ x, ushort* __restrict__ o)
{
    int i = blockIdx.x * 256 + threadIdx.x;
    float4 v = ((const float4*)x)[i];
    ushort4 r;
    r.x = f2bf(v.x); r.y = f2bf(v.y); r.z = f2bf(v.z); r.w = f2bf(v.w);
    ((ushort4*)o)[i] = r;
}

// ---------------------------------------------------------------------------
// zero the 512-float ssq accumulator (ws is poisoned each call)
// ---------------------------------------------------------------------------
__global__ void zero512_kernel(float* p) { p[threadIdx.x] = 0.f; }

// ---------------------------------------------------------------------------
// transpose w1 (128x512 fp32, k-major) -> w1t (512x128 bf16, n-major)
// ---------------------------------------------------------------------------
__global__ void w1t_kernel(const float* __restrict__ w1, ushort* __restrict__ w1t) {
    int n = blockIdx.x;            // 0..511
    int k = threadIdx.x;           // 0..127
    w1t[n * 128 + k] = f2bf(w1[k * 512 + n]);
}

// ---------------------------------------------------------------------------
// fused depthwise sparse conv (7x7 gather, bf16 X) + LayerNorm -> bf16 y1
// block = 256 thr = 4 waves, 4 tokens/wave -> 16 tokens/block
// Each lane owns channels (2*lane, 2*lane+1).
// ---------------------------------------------------------------------------
__global__ __launch_bounds__(256) void dwln_kernel(
    const ushort* __restrict__ X,     // N x 128 bf16 (xbf)
    const int*    __restrict__ nbr,   // N x 49 int32
    const float*  __restrict__ wdw,   // 49 x 128 fp32
    const float*  __restrict__ bdw,   // 128 fp32
    const float*  __restrict__ lng,   // 128 fp32
    const float*  __restrict__ lnb,   // 128 fp32
    ushort*       __restrict__ y1)    // N x 128 bf16
{
    __shared__ __align__(16) float wsm[KK2 * DIM];
    const int tid = threadIdx.x;
    for (int i = tid; i < KK2 * DIM; i += 256) wsm[i] = wdw[i];
    __syncthreads();

    const int lane = tid & 63;
    const int wv   = tid >> 6;

    const float2 bd = ((const float2*)bdw)[lane];
    const float2 g2 = ((const float2*)lng)[lane];
    const float2 be = ((const float2*)lnb)[lane];

    for (int t = 0; t < 4; ++t) {
        const int n = blockIdx.x * 16 + wv * 4 + t;
        int myidx = (lane < KK2) ? nbr[(size_t)n * KK2 + lane] : NPTS;
        float a0 = 0.f, a1 = 0.f;
        #pragma unroll
        for (int k = 0; k < KK2; ++k) {
            int idx = __shfl(myidx, k);
            if (idx < NPTS) {
                unsigned xv = ((const unsigned*)X)[(size_t)idx * 64 + lane];
                float2 wk = ((const float2*)wsm)[k * 64 + lane];
                a0 += lo16(xv) * wk.x;
                a1 += hi16(xv) * wk.y;
            }
        }
        a0 += bd.x; a1 += bd.y;
        // LayerNorm over 128 channels
        float s1 = a0 + a1;
        float s2 = a0 * a0 + a1 * a1;
        #pragma unroll
        for (int m = 1; m < 64; m <<= 1) {
            s1 += __shfl_xor(s1, m);
            s2 += __shfl_xor(s2, m);
        }
        const float mu  = s1 * (1.f / 128.f);
        const float var = s2 * (1.f / 128.f) - mu * mu;
        const float rs  = rsqrtf(var + 1e-6f);
        const float o0 = (a0 - mu) * rs * g2.x + be.x;
        const float o1 = (a1 - mu) * rs * g2.y + be.y;
        ((unsigned*)y1)[(size_t)n * 64 + lane] =
            (unsigned)f2bf(o0) | ((unsigned)f2bf(o1) << 16);
    }
}

// ---------------------------------------------------------------------------
// Shared GEMM core: C(128x128) = A(128xKTOT) * B(KTOTx128), B given n-major.
// LDS tiles XOR-swizzled in 16B chunks for conflict-free ds_read_b128.
// 4 waves; wave w owns rows [32w,32w+32) as 2 row-tiles x 8 col-tiles.
// ---------------------------------------------------------------------------
template<int KTOT>
static __device__ __forceinline__ void gemm_core(
    const ushort* __restrict__ A, int lda,
    const ushort* __restrict__ Bt, int ldb,
    int m0, int n0,
    ushort* sA, ushort* sB,
    f32x4 (&acc)[2][8], int tid)
{
    const int lane = tid & 63, wv = tid >> 6;
    const int lr = lane & 15, q = lane >> 4;

    for (int kk = 0; kk < KTOT; kk += 128) {
        #pragma unroll
        for (int i0 = 0; i0 < 2048; i0 += 256) {
            int i = i0 + tid;
            int row = i >> 4, c = i & 15;
            *(int4*)(sA + row * 128 + (((c ^ (row & 15)) << 3))) =
                *(const int4*)(A + (size_t)(m0 + row) * lda + kk + (c << 3));
        }
        #pragma unroll
        for (int i0 = 0; i0 < 2048; i0 += 256) {
            int i = i0 + tid;
            int row = i >> 4, c = i & 15;
            *(int4*)(sB + row * 128 + (((c ^ (row & 15)) << 3))) =
                *(const int4*)(Bt + (size_t)(n0 + row) * ldb + kk + (c << 3));
        }
        __syncthreads();
        #pragma unroll
        for (int ks = 0; ks < 4; ++ks) {
            const int cidx = (((4 * ks + q) ^ lr) << 3);
            bf16x8 af0 = *(const bf16x8*)(sA + ((wv << 5) + lr) * 128 + cidx);
            bf16x8 af1 = *(const bf16x8*)(sA + ((wv << 5) + 16 + lr) * 128 + cidx);
            #pragma unroll
            for (int ct = 0; ct < 8; ++ct) {
                bf16x8 bfv = *(const bf16x8*)(sB + ((ct << 4) + lr) * 128 + cidx);
                acc[0][ct] = __builtin_amdgcn_mfma_f32_16x16x32_bf16(af0, bfv, acc[0][ct], 0, 0, 0);
                acc[1][ct] = __builtin_amdgcn_mfma_f32_16x16x32_bf16(af1, bfv, acc[1][ct], 0, 0, 0);
            }
        }
        __syncthreads();
    }
}

// ---------------------------------------------------------------------------
// GEMM1: y2 = gelu(y1 @ w1 + b1); fused per-channel sum-of-squares for GRN.
// grid (1250, 4)
// ---------------------------------------------------------------------------
__global__ __launch_bounds__(256) void gemm1_kernel(
    const ushort* __restrict__ y1,    // N x 128 bf16
    const ushort* __restrict__ w1t,   // 512 x 128 bf16 (n-major)
    const float*  __restrict__ b1,    // 512 fp32
    ushort*       __restrict__ y2,    // N x 512 bf16
    float*        __restrict__ ssq)   // 512 fp32
{
    __shared__ __align__(16) ushort sA[128 * 128];
    __shared__ __align__(16) ushort sB[128 * 128];
    const int tid = threadIdx.x;
    const int m0 = blockIdx.x << 7, n0 = blockIdx.y << 7;

    f32x4 acc[2][8];
    #pragma unroll
    for (int rt = 0; rt < 2; ++rt)
        #pragma unroll
        for (int ct = 0; ct < 8; ++ct) { f32x4 z = {0.f,0.f,0.f,0.f}; acc[rt][ct] = z; }

    gemm_core<128>(y1, 128, w1t, 128, m0, n0, sA, sB, acc, tid);

    const int lane = tid & 63, wv = tid >> 6, lr = lane & 15, q = lane >> 4;
    float b1v[8], ssql[8];
    #pragma unroll
    for (int ct = 0; ct < 8; ++ct) {
        b1v[ct] = b1[n0 + (ct << 4) + lr];
        ssql[ct] = 0.f;
    }
    #pragma unroll
    for (int rt = 0; rt < 2; ++rt)
        #pragma unroll
        for (int r = 0; r < 4; ++r) {
            const int m = m0 + (wv << 5) + (rt << 4) + (q << 2) + r;
            const size_t rowoff = (size_t)m * HID + n0;
            #pragma unroll
            for (int ct = 0; ct < 8; ++ct) {
                float v = acc[rt][ct][r] + b1v[ct];
                float g = 0.5f * v * (1.0f + erff(v * 0.70710678118654752f));
                y2[rowoff + (ct << 4) + lr] = f2bf(g);
                ssql[ct] += g * g;
            }
        }
    // block-level ssq reduction: reuse sA as float[128]
    float* sred = (float*)sA;
    if (tid < 128) sred[tid] = 0.f;
    __syncthreads();
    #pragma unroll
    for (int ct = 0; ct < 8; ++ct) {
        float v = ssql[ct];
        v += __shfl_xor(v, 16);
        v += __shfl_xor(v, 32);
        if (q == 0) atomicAdd(&sred[(ct << 4) + lr], v);
    }
    __syncthreads();
    if (tid < 128) atomicAdd(&ssq[n0 + tid], sred[tid]);
}

// ---------------------------------------------------------------------------
// GRN scale: s[c] = grn_g[c] * nx[c] + 1,  nx = gx / (mean(gx) + 1e-6)
// single block, 512 threads
// ---------------------------------------------------------------------------
__global__ void grn_prep_kernel(const float* __restrict__ ssq,
                                const float* __restrict__ grn_g,
                                float* __restrict__ s)
{
    __shared__ float red[9];
    const int tid = threadIdx.x;
    const float gx = sqrtf(ssq[tid]);
    float v = gx;
    #pragma unroll
    for (int m = 1; m < 64; m <<= 1) v += __shfl_xor(v, m);
    if ((tid & 63) == 0) red[tid >> 6] = v;
    __syncthreads();
    if (tid == 0) {
        float t = 0.f;
        for (int i = 0; i < 8; ++i) t += red[i];
        red[8] = t;
    }
    __syncthreads();
    const float mean = red[8] * (1.f / 512.f);
    s[tid] = grn_g[tid] * (gx / (mean + 1e-6f)) + 1.0f;
}

// ---------------------------------------------------------------------------
// Fold GRN scale into w2 (transposed, n-major, bf16) and build the constant
// bias vector bvec[j] = sum_k grn_b[k]*w2[k,j] + b2[j].   grid 128 x 256thr
// ---------------------------------------------------------------------------
__global__ __launch_bounds__(256) void prep_w2_kernel(
    const float* __restrict__ s,      // 512
    const float* __restrict__ w2,     // 512 x 128 fp32 (k-major)
    const float* __restrict__ grn_b,  // 512 fp32
    const float* __restrict__ b2,     // 128 fp32
    ushort*      __restrict__ w2st,   // 128 x 512 bf16 (n-major, scaled)
    float*       __restrict__ bvec)   // 128 fp32
{
    __shared__ float r4[4];
    const int j = blockIdx.x;
    const int tid = threadIdx.x;
    float part = 0.f;
    for (int k = tid; k < HID; k += 256) {
        float wv = w2[k * 128 + j];
        w2st[j * HID + k] = f2bf(s[k] * wv);
        part += grn_b[k] * wv;
    }
    #pragma unroll
    for (int m = 1; m < 64; m <<= 1) part += __shfl_xor(part, m);
    if ((tid & 63) == 0) r4[tid >> 6] = part;
    __syncthreads();
    if (tid == 0)
        bvec[j] = r4[0] + r4[1] + r4[2] + r4[3] + b2[j];
}

// ---------------------------------------------------------------------------
// GEMM2: out = y2_grn @ w2 + bvec + residual   (GRN scale folded into w2st)
// grid 1250.  Output fp32; optional bf16 side-copy for next layer's gather.
// ---------------------------------------------------------------------------
__global__ __launch_bounds__(256) void gemm2_kernel(
    const ushort* __restrict__ y2,      // N x 512 bf16
    const ushort* __restrict__ w2st,    // 128 x 512 bf16 (n-major)
    const float*  __restrict__ bvec,    // 128
    const float*  __restrict__ resid,   // N x 128 fp32
    float*        __restrict__ outf,    // N x 128 fp32
    ushort*       __restrict__ xbfout)  // N x 128 bf16 (or null)
{
    __shared__ __align__(16) ushort sA[128 * 128];
    __shared__ __align__(16) ushort sB[128 * 128];
    const int tid = threadIdx.x;
    const int m0 = blockIdx.x << 7;

    f32x4 acc[2][8];
    #pragma unroll
    for (int rt = 0; rt < 2; ++rt)
        #pragma unroll
        for (int ct = 0; ct < 8; ++ct) { f32x4 z = {0.f,0.f,0.f,0.f}; acc[rt][ct] = z; }

    gemm_core<512>(y2, 512, w2st, 512, m0, 0, sA, sB, acc, tid);

    const int lane = tid & 63, wv = tid >> 6, lr = lane & 15, q = lane >> 4;
    float bv[8];
    #pragma unroll
    for (int ct = 0; ct < 8; ++ct) bv[ct] = bvec[(ct << 4) + lr];

    #pragma unroll
    for (int rt = 0; rt < 2; ++rt)
        #pragma unroll
        for (int r = 0; r < 4; ++r) {
            const int m = m0 + (wv << 5) + (rt << 4) + (q << 2) + r;
            const size_t base = (size_t)m * DIM;
            #pragma unroll
            for (int ct = 0; ct < 8; ++ct) {
                const int j = (ct << 4) + lr;
                float v = acc[rt][ct][r] + bv[ct] + resid[base + j];
                outf[base + j] = v;
                if (xbfout) xbfout[base + j] = f2bf(v);
            }
        }
}

// ---------------------------------------------------------------------------
extern "C" void kernel_launch(void* const* d_in, const int* in_sizes, int n_in,
                              void* d_out, int out_size, void* d_ws, size_t ws_size,
                              hipStream_t stream)
{
    const float* feats = (const float*)d_in[0];
    const float* w_dw  = (const float*)d_in[1];
    const float* b_dw  = (const float*)d_in[2];
    const float* ln_g  = (const float*)d_in[3];
    const float* ln_b  = (const float*)d_in[4];
    const float* w1    = (const float*)d_in[5];
    const float* b1    = (const float*)d_in[6];
    const float* grn_g = (const float*)d_in[7];
    const float* grn_b = (const float*)d_in[8];
    const float* w2    = (const float*)d_in[9];
    const float* b2    = (const float*)d_in[10];
    const int*   nbr   = (const int*)d_in[11];

    char* ws = (char*)d_ws;
    size_t o = 0;
    ushort* y2   = (ushort*)(ws + o); o += (size_t)NPTS * HID * 2;   // 163,840,000
    ushort* y1   = (ushort*)(ws + o); o += (size_t)NPTS * DIM * 2;   //  40,960,000
    ushort* xbf  = (ushort*)(ws + o); o += (size_t)NPTS * DIM * 2;   //  40,960,000
    float*  xf32 = (float*) (ws + o); o += (size_t)NPTS * DIM * 4;   //  81,920,000
    ushort* w1t  = (ushort*)(ws + o); o += (size_t)HID * DIM * 2;
    ushort* w2st = (ushort*)(ws + o); o += (size_t)HID * DIM * 2;
    float*  sbuf = (float*) (ws + o); o += 2048;
    float*  ssq  = (float*) (ws + o); o += 2048;
    float*  bvec = (float*) (ws + o); o += 512;

    // bf16 copy of the layer-0 input for the gather kernel
    cast_bf16_kernel<<<NPTS * DIM / 4 / 256, 256, 0, stream>>>(feats, xbf);

    for (int l = 0; l < DEPTH; ++l) {
        const float* wdw_l = w_dw  + (size_t)l * KK2 * DIM;
        const float* bdw_l = b_dw  + (size_t)l * DIM;
        const float* lng_l = ln_g  + (size_t)l * DIM;
        const float* lnb_l = ln_b  + (size_t)l * DIM;
        const float* w1_l  = w1    + (size_t)l * DIM * HID;
        const float* b1_l  = b1    + (size_t)l * HID;
        const float* gg_l  = grn_g + (size_t)l * HID;
        const float* gb_l  = grn_b + (size_t)l * HID;
        const float* w2_l  = w2    + (size_t)l * HID * DIM;
        const float* b2_l  = b2    + (size_t)l * DIM;

        zero512_kernel<<<1, 512, 0, stream>>>(ssq);
        w1t_kernel<<<512, 128, 0, stream>>>(w1_l, w1t);
        dwln_kernel<<<NPTS / 16, 256, 0, stream>>>(
            xbf, nbr, wdw_l, bdw_l, lng_l, lnb_l, y1);
        gemm1_kernel<<<dim3(NPTS / 128, 4), 256, 0, stream>>>(y1, w1t, b1_l, y2, ssq);
        grn_prep_kernel<<<1, 512, 0, stream>>>(ssq, gg_l, sbuf);
        prep_w2_kernel<<<128, 256, 0, stream>>>(sbuf, w2_l, gb_l, b2_l, w2st, bvec);
        if (l == 0) {
            // x1 = feats + y  -> fp32 master + bf16 copy for next dwln
            gemm2_kernel<<<NPTS / 128, 256, 0, stream>>>(
                y2, w2st, bvec, feats, xf32, xbf);
        } else {
            gemm2_kernel<<<NPTS / 128, 256, 0, stream>>>(
                y2, w2st, bvec, xf32, (float*)d_out, nullptr);
        }
    }
}

// Round 3
// 980.859 us; speedup vs baseline: 1.1064x; 1.1064x over previous
//
#include <hip/hip_runtime.h>
#include <hip/hip_bf16.h>

// Problem constants (from reference)
#define NPTS   160000    // B*P = 4*40000
#define DIM    128
#define HID    512
#define KK2    49        // 7x7
#define DEPTH  2

typedef __attribute__((ext_vector_type(8))) short bf16x8;
typedef __attribute__((ext_vector_type(4))) float f32x4;

static __device__ __forceinline__ ushort f2bf(float f) {
    unsigned u = __float_as_uint(f);
    return (ushort)((u + 0x7fffu + ((u >> 16) & 1u)) >> 16);
}
static __device__ __forceinline__ float bf2f(ushort h) {
    return __uint_as_float(((unsigned)h) << 16);
}
static __device__ __forceinline__ float lo16(unsigned u) { return __uint_as_float(u << 16); }
static __device__ __forceinline__ float hi16(unsigned u) { return __uint_as_float(u & 0xffff0000u); }

// ---------------------------------------------------------------------------
// fp32 -> bf16 cast (4 elems/thread), exact-size grid
// ---------------------------------------------------------------------------
__global__ __launch_bounds__(256) void cast_bf16_kernel(
    const float* __restrict__ x, ushort* __restrict__ o)
{
    int i = blockIdx.x * 256 + threadIdx.x;
    float4 v = ((const float4*)x)[i];
    ushort4 r;
    r.x = f2bf(v.x); r.y = f2bf(v.y); r.z = f2bf(v.z); r.w = f2bf(v.w);
    ((ushort4*)o)[i] = r;
}

// ---------------------------------------------------------------------------
// zero the 512-float ssq accumulator (ws is poisoned each call)
// ---------------------------------------------------------------------------
__global__ void zero512_kernel(float* p) { p[threadIdx.x] = 0.f; }

// ---------------------------------------------------------------------------
// transpose w1 (128x512 fp32, k-major) -> w1t (512x128 bf16, n-major)
// ---------------------------------------------------------------------------
__global__ void w1t_kernel(const float* __restrict__ w1, ushort* __restrict__ w1t) {
    int n = blockIdx.x;            // 0..511
    int k = threadIdx.x;           // 0..127
    w1t[n * 128 + k] = f2bf(w1[k * 512 + n]);
}

// ---------------------------------------------------------------------------
// Compact valid neighbor taps: wlist[n*49 + j] = (idx<<6)|tap for each valid
// tap (idx < NPTS), padded to even count with (0<<6)|49 (zero weight row).
// cnts[n] = valid count. One wave per token. Runs ONCE (shared by layers).
// ---------------------------------------------------------------------------
__global__ __launch_bounds__(256) void compact_kernel(
    const int* __restrict__ nbr, int* __restrict__ wlist, int* __restrict__ cnts)
{
    const int tid = threadIdx.x, lane = tid & 63, wv = tid >> 6;
    const int n = blockIdx.x * 4 + wv;
    int idx = (lane < KK2) ? nbr[(size_t)n * KK2 + lane] : NPTS;
    bool valid = idx < NPTS;
    unsigned long long mask = __ballot(valid);
    int cnt = __popcll(mask);
    int pos = __popcll(mask & ((1ull << lane) - 1ull));
    if (valid) wlist[(size_t)n * KK2 + pos] = (idx << 6) | lane;
    if (lane == 0) {
        cnts[n] = cnt;
        if (cnt & 1) wlist[(size_t)n * KK2 + cnt] = 49;  // idx 0, zero-weight tap 49
    }
}

// ---------------------------------------------------------------------------
// Depthwise sparse conv (compacted taps) + LayerNorm.  One wave per token.
// Lanes 0-31 process even list entries, lanes 32-63 odd entries (2 taps/iter).
// Lane half-index c owns channels 4c..4c+3 (8 B bf16 x-load, 16 B fp32 w).
// Depth-2 software pipeline keeps 2 gathers in flight per wave.
// ---------------------------------------------------------------------------
__global__ __launch_bounds__(256) void dwln2_kernel(
    const ushort* __restrict__ X,      // N x 128 bf16
    const int*    __restrict__ wlist,  // N x 49 packed (idx<<6)|tap
    const int*    __restrict__ cnts,   // N
    const float*  __restrict__ wdw,    // 49 x 128 fp32
    const float*  __restrict__ bdw,    // 128
    const float*  __restrict__ lng,    // 128
    const float*  __restrict__ lnb,    // 128
    ushort*       __restrict__ y1)     // N x 128 bf16
{
    __shared__ __align__(16) float wsm[50 * DIM];   // row 49 = zeros (pad tap)
    const int tid = threadIdx.x;
    for (int i = tid; i < KK2 * DIM; i += 256) wsm[i] = wdw[i];
    if (tid < DIM) wsm[KK2 * DIM + tid] = 0.f;
    __syncthreads();

    const int lane = tid & 63, wv = tid >> 6;
    const int n = blockIdx.x * 4 + wv;
    const int half = lane >> 5, c = lane & 31;

    const int cnt = cnts[n];
    const int niter = (cnt + 1) >> 1;
    const int e = wlist[(size_t)n * KK2 + lane];

    float4 a = {0.f, 0.f, 0.f, 0.f};

    int tap0; uint2 xv0;
    {
        int ea = __shfl(e, 0), eb = __shfl(e, 1);
        int ee = half ? eb : ea;
        tap0 = ee & 63;
        xv0 = *(const uint2*)(X + (size_t)(ee >> 6) * DIM + c * 4);
    }
    for (int j = 0; j < niter; ++j) {
        int tap1 = 49; uint2 xv1 = {0u, 0u};
        if (j + 1 < niter) {
            int ea = __shfl(e, 2 * j + 2), eb = __shfl(e, 2 * j + 3);
            int ee = half ? eb : ea;
            tap1 = ee & 63;
            xv1 = *(const uint2*)(X + (size_t)(ee >> 6) * DIM + c * 4);
        }
        float4 w4 = *(const float4*)(wsm + tap0 * DIM + c * 4);
        a.x += lo16(xv0.x) * w4.x;
        a.y += hi16(xv0.x) * w4.y;
        a.z += lo16(xv0.y) * w4.z;
        a.w += hi16(xv0.y) * w4.w;
        tap0 = tap1; xv0 = xv1;
    }

    // combine tap-halves (lanes c and c+32 hold same channels)
    a.x += __shfl_xor(a.x, 32);
    a.y += __shfl_xor(a.y, 32);
    a.z += __shfl_xor(a.z, 32);
    a.w += __shfl_xor(a.w, 32);

    const float4 bd = ((const float4*)bdw)[c];
    a.x += bd.x; a.y += bd.y; a.z += bd.z; a.w += bd.w;

    // LayerNorm over 128 channels (32 lanes x 4, duplicated across halves)
    float s1 = a.x + a.y + a.z + a.w;
    float s2 = a.x * a.x + a.y * a.y + a.z * a.z + a.w * a.w;
    #pragma unroll
    for (int m = 1; m < 32; m <<= 1) {
        s1 += __shfl_xor(s1, m);
        s2 += __shfl_xor(s2, m);
    }
    const float mu  = s1 * (1.f / 128.f);
    const float var = s2 * (1.f / 128.f) - mu * mu;
    const float rs  = rsqrtf(var + 1e-6f);

    if (half == 0) {
        const float4 g  = ((const float4*)lng)[c];
        const float4 be = ((const float4*)lnb)[c];
        ushort4 r;
        r.x = f2bf((a.x - mu) * rs * g.x + be.x);
        r.y = f2bf((a.y - mu) * rs * g.y + be.y);
        r.z = f2bf((a.z - mu) * rs * g.z + be.z);
        r.w = f2bf((a.w - mu) * rs * g.w + be.w);
        ((ushort4*)(y1 + (size_t)n * DIM))[c] = r;
    }
}

// ---------------------------------------------------------------------------
// Shared GEMM core: C(128x128) = A(128xKTOT) * B(KTOTx128), B given n-major.
// LDS tiles XOR-swizzled in 16B chunks for conflict-free ds_read_b128.
// 4 waves; wave w owns rows [32w,32w+32) as 2 row-tiles x 8 col-tiles.
// ---------------------------------------------------------------------------
template<int KTOT>
static __device__ __forceinline__ void gemm_core(
    const ushort* __restrict__ A, int lda,
    const ushort* __restrict__ Bt, int ldb,
    int m0, int n0,
    ushort* sA, ushort* sB,
    f32x4 (&acc)[2][8], int tid)
{
    const int lane = tid & 63, wv = tid >> 6;
    const int lr = lane & 15, q = lane >> 4;

    for (int kk = 0; kk < KTOT; kk += 128) {
        #pragma unroll
        for (int i0 = 0; i0 < 2048; i0 += 256) {
            int i = i0 + tid;
            int row = i >> 4, c = i & 15;
            *(int4*)(sA + row * 128 + (((c ^ (row & 15)) << 3))) =
                *(const int4*)(A + (size_t)(m0 + row) * lda + kk + (c << 3));
        }
        #pragma unroll
        for (int i0 = 0; i0 < 2048; i0 += 256) {
            int i = i0 + tid;
            int row = i >> 4, c = i & 15;
            *(int4*)(sB + row * 128 + (((c ^ (row & 15)) << 3))) =
                *(const int4*)(Bt + (size_t)(n0 + row) * ldb + kk + (c << 3));
        }
        __syncthreads();
        #pragma unroll
        for (int ks = 0; ks < 4; ++ks) {
            const int cidx = (((4 * ks + q) ^ lr) << 3);
            bf16x8 af0 = *(const bf16x8*)(sA + ((wv << 5) + lr) * 128 + cidx);
            bf16x8 af1 = *(const bf16x8*)(sA + ((wv << 5) + 16 + lr) * 128 + cidx);
            #pragma unroll
            for (int ct = 0; ct < 8; ++ct) {
                bf16x8 bfv = *(const bf16x8*)(sB + ((ct << 4) + lr) * 128 + cidx);
                acc[0][ct] = __builtin_amdgcn_mfma_f32_16x16x32_bf16(af0, bfv, acc[0][ct], 0, 0, 0);
                acc[1][ct] = __builtin_amdgcn_mfma_f32_16x16x32_bf16(af1, bfv, acc[1][ct], 0, 0, 0);
            }
        }
        __syncthreads();
    }
}

// ---------------------------------------------------------------------------
// GEMM1: y2 = gelu(y1 @ w1 + b1); fused per-channel sum-of-squares for GRN.
// grid (1250, 4)
// ---------------------------------------------------------------------------
__global__ __launch_bounds__(256) void gemm1_kernel(
    const ushort* __restrict__ y1,    // N x 128 bf16
    const ushort* __restrict__ w1t,   // 512 x 128 bf16 (n-major)
    const float*  __restrict__ b1,    // 512 fp32
    ushort*       __restrict__ y2,    // N x 512 bf16
    float*        __restrict__ ssq)   // 512 fp32
{
    __shared__ __align__(16) ushort sA[128 * 128];
    __shared__ __align__(16) ushort sB[128 * 128];
    const int tid = threadIdx.x;
    const int m0 = blockIdx.x << 7, n0 = blockIdx.y << 7;

    f32x4 acc[2][8];
    #pragma unroll
    for (int rt = 0; rt < 2; ++rt)
        #pragma unroll
        for (int ct = 0; ct < 8; ++ct) { f32x4 z = {0.f,0.f,0.f,0.f}; acc[rt][ct] = z; }

    gemm_core<128>(y1, 128, w1t, 128, m0, n0, sA, sB, acc, tid);

    const int lane = tid & 63, wv = tid >> 6, lr = lane & 15, q = lane >> 4;
    float b1v[8], ssql[8];
    #pragma unroll
    for (int ct = 0; ct < 8; ++ct) {
        b1v[ct] = b1[n0 + (ct << 4) + lr];
        ssql[ct] = 0.f;
    }
    #pragma unroll
    for (int rt = 0; rt < 2; ++rt)
        #pragma unroll
        for (int r = 0; r < 4; ++r) {
            const int m = m0 + (wv << 5) + (rt << 4) + (q << 2) + r;
            const size_t rowoff = (size_t)m * HID + n0;
            #pragma unroll
            for (int ct = 0; ct < 8; ++ct) {
                float v = acc[rt][ct][r] + b1v[ct];
                float g = 0.5f * v * (1.0f + erff(v * 0.70710678118654752f));
                y2[rowoff + (ct << 4) + lr] = f2bf(g);
                ssql[ct] += g * g;
            }
        }
    // block-level ssq reduction: reuse sA as float[128]
    float* sred = (float*)sA;
    if (tid < 128) sred[tid] = 0.f;
    __syncthreads();
    #pragma unroll
    for (int ct = 0; ct < 8; ++ct) {
        float v = ssql[ct];
        v += __shfl_xor(v, 16);
        v += __shfl_xor(v, 32);
        if (q == 0) atomicAdd(&sred[(ct << 4) + lr], v);
    }
    __syncthreads();
    if (tid < 128) atomicAdd(&ssq[n0 + tid], sred[tid]);
}

// ---------------------------------------------------------------------------
// GRN scale: s[c] = grn_g[c] * nx[c] + 1,  nx = gx / (mean(gx) + 1e-6)
// single block, 512 threads
// ---------------------------------------------------------------------------
__global__ void grn_prep_kernel(const float* __restrict__ ssq,
                                const float* __restrict__ grn_g,
                                float* __restrict__ s)
{
    __shared__ float red[9];
    const int tid = threadIdx.x;
    const float gx = sqrtf(ssq[tid]);
    float v = gx;
    #pragma unroll
    for (int m = 1; m < 64; m <<= 1) v += __shfl_xor(v, m);
    if ((tid & 63) == 0) red[tid >> 6] = v;
    __syncthreads();
    if (tid == 0) {
        float t = 0.f;
        for (int i = 0; i < 8; ++i) t += red[i];
        red[8] = t;
    }
    __syncthreads();
    const float mean = red[8] * (1.f / 512.f);
    s[tid] = grn_g[tid] * (gx / (mean + 1e-6f)) + 1.0f;
}

// ---------------------------------------------------------------------------
// Fold GRN scale into w2 (transposed, n-major, bf16) and build the constant
// bias vector bvec[j] = sum_k grn_b[k]*w2[k,j] + b2[j].   grid 128 x 256thr
// ---------------------------------------------------------------------------
__global__ __launch_bounds__(256) void prep_w2_kernel(
    const float* __restrict__ s,      // 512
    const float* __restrict__ w2,     // 512 x 128 fp32 (k-major)
    const float* __restrict__ grn_b,  // 512 fp32
    const float* __restrict__ b2,     // 128 fp32
    ushort*      __restrict__ w2st,   // 128 x 512 bf16 (n-major, scaled)
    float*       __restrict__ bvec)   // 128 fp32
{
    __shared__ float r4[4];
    const int j = blockIdx.x;
    const int tid = threadIdx.x;
    float part = 0.f;
    for (int k = tid; k < HID; k += 256) {
        float wv = w2[k * 128 + j];
        w2st[j * HID + k] = f2bf(s[k] * wv);
        part += grn_b[k] * wv;
    }
    #pragma unroll
    for (int m = 1; m < 64; m <<= 1) part += __shfl_xor(part, m);
    if ((tid & 63) == 0) r4[tid >> 6] = part;
    __syncthreads();
    if (tid == 0)
        bvec[j] = r4[0] + r4[1] + r4[2] + r4[3] + b2[j];
}

// ---------------------------------------------------------------------------
// GEMM2: out = y2_grn @ w2 + bvec + residual   (GRN scale folded into w2st)
// grid 1250.  Residual is bf16; outputs fp32 (final) and/or bf16 (next layer).
// ---------------------------------------------------------------------------
__global__ __launch_bounds__(256) void gemm2_kernel(
    const ushort* __restrict__ y2,      // N x 512 bf16
    const ushort* __restrict__ w2st,    // 128 x 512 bf16 (n-major)
    const float*  __restrict__ bvec,    // 128
    const ushort* __restrict__ resid,   // N x 128 bf16
    float*        __restrict__ outf,    // N x 128 fp32 (or null)
    ushort*       __restrict__ xbfout)  // N x 128 bf16 (or null)
{
    __shared__ __align__(16) ushort sA[128 * 128];
    __shared__ __align__(16) ushort sB[128 * 128];
    const int tid = threadIdx.x;
    const int m0 = blockIdx.x << 7;

    f32x4 acc[2][8];
    #pragma unroll
    for (int rt = 0; rt < 2; ++rt)
        #pragma unroll
        for (int ct = 0; ct < 8; ++ct) { f32x4 z = {0.f,0.f,0.f,0.f}; acc[rt][ct] = z; }

    gemm_core<512>(y2, 512, w2st, 512, m0, 0, sA, sB, acc, tid);

    const int lane = tid & 63, wv = tid >> 6, lr = lane & 15, q = lane >> 4;
    float bv[8];
    #pragma unroll
    for (int ct = 0; ct < 8; ++ct) bv[ct] = bvec[(ct << 4) + lr];

    #pragma unroll
    for (int rt = 0; rt < 2; ++rt)
        #pragma unroll
        for (int r = 0; r < 4; ++r) {
            const int m = m0 + (wv << 5) + (rt << 4) + (q << 2) + r;
            const size_t base = (size_t)m * DIM;
            #pragma unroll
            for (int ct = 0; ct < 8; ++ct) {
                const int j = (ct << 4) + lr;
                float v = acc[rt][ct][r] + bv[ct] + bf2f(resid[base + j]);
                if (outf)   outf[base + j] = v;
                if (xbfout) xbfout[base + j] = f2bf(v);
            }
        }
}

// ---------------------------------------------------------------------------
extern "C" void kernel_launch(void* const* d_in, const int* in_sizes, int n_in,
                              void* d_out, int out_size, void* d_ws, size_t ws_size,
                              hipStream_t stream)
{
    const float* feats = (const float*)d_in[0];
    const float* w_dw  = (const float*)d_in[1];
    const float* b_dw  = (const float*)d_in[2];
    const float* ln_g  = (const float*)d_in[3];
    const float* ln_b  = (const float*)d_in[4];
    const float* w1    = (const float*)d_in[5];
    const float* b1    = (const float*)d_in[6];
    const float* grn_g = (const float*)d_in[7];
    const float* grn_b = (const float*)d_in[8];
    const float* w2    = (const float*)d_in[9];
    const float* b2    = (const float*)d_in[10];
    const int*   nbr   = (const int*)d_in[11];

    char* ws = (char*)d_ws;
    size_t o = 0;
    ushort* y2    = (ushort*)(ws + o); o += (size_t)NPTS * HID * 2;        // 160 MB
    ushort* y1    = (ushort*)(ws + o); o += (size_t)NPTS * DIM * 2;        //  40 MB
    ushort* xbf   = (ushort*)(ws + o); o += (size_t)NPTS * DIM * 2;        //  40 MB
    int*    wlist = (int*)   (ws + o); o += ((size_t)NPTS * KK2 + 64) * 4; //  31 MB
    int*    cnts  = (int*)   (ws + o); o += (size_t)NPTS * 4;
    ushort* w1t   = (ushort*)(ws + o); o += (size_t)HID * DIM * 2;
    ushort* w2st  = (ushort*)(ws + o); o += (size_t)HID * DIM * 2;
    float*  sbuf  = (float*) (ws + o); o += 2048;
    float*  ssq   = (float*) (ws + o); o += 2048;
    float*  bvec  = (float*) (ws + o); o += 512;

    // bf16 copy of layer-0 input; compacted neighbor lists (shared by layers)
    cast_bf16_kernel<<<NPTS * DIM / 4 / 256, 256, 0, stream>>>(feats, xbf);
    compact_kernel<<<NPTS / 4, 256, 0, stream>>>(nbr, wlist, cnts);

    for (int l = 0; l < DEPTH; ++l) {
        const float* wdw_l = w_dw  + (size_t)l * KK2 * DIM;
        const float* bdw_l = b_dw  + (size_t)l * DIM;
        const float* lng_l = ln_g  + (size_t)l * DIM;
        const float* lnb_l = ln_b  + (size_t)l * DIM;
        const float* w1_l  = w1    + (size_t)l * DIM * HID;
        const float* b1_l  = b1    + (size_t)l * HID;
        const float* gg_l  = grn_g + (size_t)l * HID;
        const float* gb_l  = grn_b + (size_t)l * HID;
        const float* w2_l  = w2    + (size_t)l * HID * DIM;
        const float* b2_l  = b2    + (size_t)l * DIM;

        zero512_kernel<<<1, 512, 0, stream>>>(ssq);
        w1t_kernel<<<512, 128, 0, stream>>>(w1_l, w1t);
        dwln2_kernel<<<NPTS / 4, 256, 0, stream>>>(
            xbf, wlist, cnts, wdw_l, bdw_l, lng_l, lnb_l, y1);
        gemm1_kernel<<<dim3(NPTS / 128, 4), 256, 0, stream>>>(y1, w1t, b1_l, y2, ssq);
        grn_prep_kernel<<<1, 512, 0, stream>>>(ssq, gg_l, sbuf);
        prep_w2_kernel<<<128, 256, 0, stream>>>(sbuf, w2_l, gb_l, b2_l, w2st, bvec);
        if (l == 0) {
            gemm2_kernel<<<NPTS / 128, 256, 0, stream>>>(
                y2, w2st, bvec, xbf, nullptr, xbf);
        } else {
            gemm2_kernel<<<NPTS / 128, 256, 0, stream>>>(
                y2, w2st, bvec, xbf, (float*)d_out, nullptr);
        }
    }
}

// Round 4
// 866.299 us; speedup vs baseline: 1.2527x; 1.1322x over previous
//
#include <hip/hip_runtime.h>
#include <hip/hip_bf16.h>

// Problem constants (from reference)
#define NPTS   160000    // B*P = 4*40000
#define DIM    128
#define HID    512
#define KK2    49        // 7x7
#define DEPTH  2

typedef __attribute__((ext_vector_type(8))) short bf16x8;
typedef __attribute__((ext_vector_type(4))) float f32x4;

static __device__ __forceinline__ ushort f2bf(float f) {
    unsigned u = __float_as_uint(f);
    return (ushort)((u + 0x7fffu + ((u >> 16) & 1u)) >> 16);
}
static __device__ __forceinline__ float bf2f(ushort h) {
    return __uint_as_float(((unsigned)h) << 16);
}
static __device__ __forceinline__ float lo16(unsigned u) { return __uint_as_float(u << 16); }
static __device__ __forceinline__ float hi16(unsigned u) { return __uint_as_float(u & 0xffff0000u); }

// ---------------------------------------------------------------------------
// fp32 -> bf16 cast (4 elems/thread), exact-size grid
// ---------------------------------------------------------------------------
__global__ __launch_bounds__(256) void cast_bf16_kernel(
    const float* __restrict__ x, ushort* __restrict__ o)
{
    int i = blockIdx.x * 256 + threadIdx.x;
    float4 v = ((const float4*)x)[i];
    ushort4 r;
    r.x = f2bf(v.x); r.y = f2bf(v.y); r.z = f2bf(v.z); r.w = f2bf(v.w);
    ((ushort4*)o)[i] = r;
}

// ---------------------------------------------------------------------------
// transpose w1 (128x512 fp32) -> w1t (512x128 bf16, n-major); also zeros ssq
// ---------------------------------------------------------------------------
__global__ void w1t_kernel(const float* __restrict__ w1, ushort* __restrict__ w1t,
                           float* __restrict__ ssq) {
    int n = blockIdx.x;            // 0..511
    int k = threadIdx.x;           // 0..127
    w1t[n * 128 + k] = f2bf(w1[k * 512 + n]);
    if (n < 4) ssq[n * 128 + k] = 0.f;
}

// ---------------------------------------------------------------------------
// Compact valid neighbor taps into round-of-4 entries:
//   entry = idx*256 + tap   (idx*256 = byte offset of X row; tap in low 8b)
// padded to a multiple of 4 with entry 49 (idx 0, tap 49 = zero weight row).
// wl stride = 52 ints/token; nrounds[n] = ceil(cnt/4).  One wave per token.
// ---------------------------------------------------------------------------
__global__ __launch_bounds__(256) void compact2_kernel(
    const int* __restrict__ nbr, int* __restrict__ wl, int* __restrict__ nrounds)
{
    const int tid = threadIdx.x, lane = tid & 63, wv = tid >> 6;
    const int n = blockIdx.x * 4 + wv;
    int idx = (lane < KK2) ? nbr[(size_t)n * KK2 + lane] : NPTS;
    bool valid = idx < NPTS;
    unsigned long long mask = __ballot(valid);
    int cnt = __popcll(mask);
    int pos = __popcll(mask & ((1ull << lane) - 1ull));
    int* row = wl + (size_t)n * 52;
    if (valid) row[pos] = (idx << 8) | lane;
    int padded = (cnt + 3) & ~3;
    if (lane < padded - cnt) row[cnt + lane] = 49;
    if (lane == 0) nrounds[n] = padded >> 2;
}

// ---------------------------------------------------------------------------
// Depthwise sparse conv + LayerNorm, v3.
// 1024-thr block = 16 waves = 16 tokens; weights staged once per block.
// Per wave: lane = slot*16 + cg; slot = tap-within-round (4 taps/round),
// cg = 8-channel group (uint4 x-load).  Entries read directly from wl
// (16-lane broadcast), prefetched 2 rounds ahead; x gathers 1 round ahead.
// LDS weight layout [cg][tap][8] -> 2-way-only bank aliasing (free).
// ---------------------------------------------------------------------------
__global__ __launch_bounds__(1024) void dwln3_kernel(
    const ushort* __restrict__ X,      // N x 128 bf16
    const int*    __restrict__ wl,     // N x 52 entries
    const int*    __restrict__ nrounds,// N
    const float*  __restrict__ wdw,    // 49 x 128 fp32
    const float*  __restrict__ bdw,    // 128
    const float*  __restrict__ lng,    // 128
    const float*  __restrict__ lnb,    // 128
    ushort*       __restrict__ y1)     // N x 128 bf16
{
    __shared__ __align__(16) float wsm[16 * 50 * 8];   // [cg][tap][8]
    const int tid = threadIdx.x;
    #pragma unroll
    for (int i0 = 0; i0 < 2048; i0 += 1024) {
        int i = i0 + tid;
        if (i < 1568) {
            int tap = i >> 5, rem = i & 31, cg = rem >> 1, q = rem & 1;
            ((float4*)wsm)[(cg * 50 + tap) * 2 + q] = ((const float4*)wdw)[i];
        }
    }
    if (tid < 32) {
        float4 z = {0.f, 0.f, 0.f, 0.f};
        int cg = tid >> 1, q = tid & 1;
        ((float4*)wsm)[(cg * 50 + 49) * 2 + q] = z;
    }
    __syncthreads();

    const int lane = tid & 63, wv = tid >> 6;
    const int n = blockIdx.x * 16 + wv;
    const int slot = lane >> 4, cg = lane & 15;
    const int R = nrounds[n];
    const int* row = wl + (size_t)n * 52;
    const float* wcg = wsm + cg * 400;
    const char* Xb = (const char*)X + cg * 16;

    float a[8] = {0.f, 0.f, 0.f, 0.f, 0.f, 0.f, 0.f, 0.f};

    int e0 = row[slot];
    int e1 = (R > 1) ? row[4 + slot] : 49;
    uint4 x0 = *(const uint4*)(Xb + (e0 & ~255));
    for (int r = 0; r < R; ++r) {
        int e2 = (r + 2 < R) ? row[(r + 2) * 4 + slot] : 49;
        uint4 x1 = {0u, 0u, 0u, 0u};
        if (r + 1 < R) x1 = *(const uint4*)(Xb + (e1 & ~255));
        const float* wp = wcg + (e0 & 255) * 8;
        float4 wa = *(const float4*)wp;
        float4 wb = *(const float4*)(wp + 4);
        a[0] += lo16(x0.x) * wa.x;  a[1] += hi16(x0.x) * wa.y;
        a[2] += lo16(x0.y) * wa.z;  a[3] += hi16(x0.y) * wa.w;
        a[4] += lo16(x0.z) * wb.x;  a[5] += hi16(x0.z) * wb.y;
        a[6] += lo16(x0.w) * wb.z;  a[7] += hi16(x0.w) * wb.w;
        e0 = e1; e1 = e2; x0 = x1;
    }

    // combine the 4 tap-slots (lanes with equal cg)
    #pragma unroll
    for (int j = 0; j < 8; ++j) {
        a[j] += __shfl_xor(a[j], 16);
        a[j] += __shfl_xor(a[j], 32);
    }

    const float4 bda = ((const float4*)bdw)[cg * 2];
    const float4 bdb = ((const float4*)bdw)[cg * 2 + 1];
    a[0] += bda.x; a[1] += bda.y; a[2] += bda.z; a[3] += bda.w;
    a[4] += bdb.x; a[5] += bdb.y; a[6] += bdb.z; a[7] += bdb.w;

    float s1 = 0.f, s2 = 0.f;
    #pragma unroll
    for (int j = 0; j < 8; ++j) { s1 += a[j]; s2 += a[j] * a[j]; }
    #pragma unroll
    for (int m = 1; m < 16; m <<= 1) {
        s1 += __shfl_xor(s1, m);
        s2 += __shfl_xor(s2, m);
    }
    const float mu  = s1 * (1.f / 128.f);
    const float var = s2 * (1.f / 128.f) - mu * mu;
    const float rs  = rsqrtf(var + 1e-6f);

    if (slot == 0) {
        const float4 ga = ((const float4*)lng)[cg * 2];
        const float4 gb = ((const float4*)lng)[cg * 2 + 1];
        const float4 ba = ((const float4*)lnb)[cg * 2];
        const float4 bb = ((const float4*)lnb)[cg * 2 + 1];
        uint4 r;
        r.x = (unsigned)f2bf((a[0] - mu) * rs * ga.x + ba.x)
            | ((unsigned)f2bf((a[1] - mu) * rs * ga.y + ba.y) << 16);
        r.y = (unsigned)f2bf((a[2] - mu) * rs * ga.z + ba.z)
            | ((unsigned)f2bf((a[3] - mu) * rs * ga.w + ba.w) << 16);
        r.z = (unsigned)f2bf((a[4] - mu) * rs * gb.x + bb.x)
            | ((unsigned)f2bf((a[5] - mu) * rs * gb.y + bb.y) << 16);
        r.w = (unsigned)f2bf((a[6] - mu) * rs * gb.z + bb.z)
            | ((unsigned)f2bf((a[7] - mu) * rs * gb.w + bb.w) << 16);
        ((uint4*)(y1 + (size_t)n * DIM))[cg] = r;
    }
}

// ---------------------------------------------------------------------------
// Shared GEMM core: C(128x128) = A(128xKTOT) * B(KTOTx128), B given n-major.
// LDS tiles XOR-swizzled in 16B chunks for conflict-free ds_read_b128.
// ---------------------------------------------------------------------------
template<int KTOT>
static __device__ __forceinline__ void gemm_core(
    const ushort* __restrict__ A, int lda,
    const ushort* __restrict__ Bt, int ldb,
    int m0, int n0,
    ushort* sA, ushort* sB,
    f32x4 (&acc)[2][8], int tid)
{
    const int lane = tid & 63, wv = tid >> 6;
    const int lr = lane & 15, q = lane >> 4;

    for (int kk = 0; kk < KTOT; kk += 128) {
        #pragma unroll
        for (int i0 = 0; i0 < 2048; i0 += 256) {
            int i = i0 + tid;
            int row = i >> 4, c = i & 15;
            *(int4*)(sA + row * 128 + (((c ^ (row & 15)) << 3))) =
                *(const int4*)(A + (size_t)(m0 + row) * lda + kk + (c << 3));
        }
        #pragma unroll
        for (int i0 = 0; i0 < 2048; i0 += 256) {
            int i = i0 + tid;
            int row = i >> 4, c = i & 15;
            *(int4*)(sB + row * 128 + (((c ^ (row & 15)) << 3))) =
                *(const int4*)(Bt + (size_t)(n0 + row) * ldb + kk + (c << 3));
        }
        __syncthreads();
        #pragma unroll
        for (int ks = 0; ks < 4; ++ks) {
            const int cidx = (((4 * ks + q) ^ lr) << 3);
            bf16x8 af0 = *(const bf16x8*)(sA + ((wv << 5) + lr) * 128 + cidx);
            bf16x8 af1 = *(const bf16x8*)(sA + ((wv << 5) + 16 + lr) * 128 + cidx);
            #pragma unroll
            for (int ct = 0; ct < 8; ++ct) {
                bf16x8 bfv = *(const bf16x8*)(sB + ((ct << 4) + lr) * 128 + cidx);
                acc[0][ct] = __builtin_amdgcn_mfma_f32_16x16x32_bf16(af0, bfv, acc[0][ct], 0, 0, 0);
                acc[1][ct] = __builtin_amdgcn_mfma_f32_16x16x32_bf16(af1, bfv, acc[1][ct], 0, 0, 0);
            }
        }
        __syncthreads();
    }
}

// ---------------------------------------------------------------------------
// GEMM1: y2 = gelu(y1 @ w1 + b1); fused per-channel sum-of-squares for GRN.
// grid (1250, 4)
// ---------------------------------------------------------------------------
__global__ __launch_bounds__(256) void gemm1_kernel(
    const ushort* __restrict__ y1,    // N x 128 bf16
    const ushort* __restrict__ w1t,   // 512 x 128 bf16 (n-major)
    const float*  __restrict__ b1,    // 512 fp32
    ushort*       __restrict__ y2,    // N x 512 bf16
    float*        __restrict__ ssq)   // 512 fp32
{
    __shared__ __align__(16) ushort sA[128 * 128];
    __shared__ __align__(16) ushort sB[128 * 128];
    const int tid = threadIdx.x;
    const int m0 = blockIdx.x << 7, n0 = blockIdx.y << 7;

    f32x4 acc[2][8];
    #pragma unroll
    for (int rt = 0; rt < 2; ++rt)
        #pragma unroll
        for (int ct = 0; ct < 8; ++ct) { f32x4 z = {0.f,0.f,0.f,0.f}; acc[rt][ct] = z; }

    gemm_core<128>(y1, 128, w1t, 128, m0, n0, sA, sB, acc, tid);

    const int lane = tid & 63, wv = tid >> 6, lr = lane & 15, q = lane >> 4;
    float b1v[8], ssql[8];
    #pragma unroll
    for (int ct = 0; ct < 8; ++ct) {
        b1v[ct] = b1[n0 + (ct << 4) + lr];
        ssql[ct] = 0.f;
    }
    #pragma unroll
    for (int rt = 0; rt < 2; ++rt)
        #pragma unroll
        for (int r = 0; r < 4; ++r) {
            const int m = m0 + (wv << 5) + (rt << 4) + (q << 2) + r;
            const size_t rowoff = (size_t)m * HID + n0;
            #pragma unroll
            for (int ct = 0; ct < 8; ++ct) {
                float v = acc[rt][ct][r] + b1v[ct];
                float g = 0.5f * v * (1.0f + erff(v * 0.70710678118654752f));
                y2[rowoff + (ct << 4) + lr] = f2bf(g);
                ssql[ct] += g * g;
            }
        }
    float* sred = (float*)sA;
    if (tid < 128) sred[tid] = 0.f;
    __syncthreads();
    #pragma unroll
    for (int ct = 0; ct < 8; ++ct) {
        float v = ssql[ct];
        v += __shfl_xor(v, 16);
        v += __shfl_xor(v, 32);
        if (q == 0) atomicAdd(&sred[(ct << 4) + lr], v);
    }
    __syncthreads();
    if (tid < 128) atomicAdd(&ssq[n0 + tid], sred[tid]);
}

// ---------------------------------------------------------------------------
// GRN scale: s[c] = grn_g[c] * nx[c] + 1
// ---------------------------------------------------------------------------
__global__ void grn_prep_kernel(const float* __restrict__ ssq,
                                const float* __restrict__ grn_g,
                                float* __restrict__ s)
{
    __shared__ float red[9];
    const int tid = threadIdx.x;
    const float gx = sqrtf(ssq[tid]);
    float v = gx;
    #pragma unroll
    for (int m = 1; m < 64; m <<= 1) v += __shfl_xor(v, m);
    if ((tid & 63) == 0) red[tid >> 6] = v;
    __syncthreads();
    if (tid == 0) {
        float t = 0.f;
        for (int i = 0; i < 8; ++i) t += red[i];
        red[8] = t;
    }
    __syncthreads();
    const float mean = red[8] * (1.f / 512.f);
    s[tid] = grn_g[tid] * (gx / (mean + 1e-6f)) + 1.0f;
}

// ---------------------------------------------------------------------------
// Fold GRN scale into w2 (transposed, n-major, bf16) + constant bias vector
// ---------------------------------------------------------------------------
__global__ __launch_bounds__(256) void prep_w2_kernel(
    const float* __restrict__ s,      // 512
    const float* __restrict__ w2,     // 512 x 128 fp32 (k-major)
    const float* __restrict__ grn_b,  // 512 fp32
    const float* __restrict__ b2,     // 128 fp32
    ushort*      __restrict__ w2st,   // 128 x 512 bf16 (n-major, scaled)
    float*       __restrict__ bvec)   // 128 fp32
{
    __shared__ float r4[4];
    const int j = blockIdx.x;
    const int tid = threadIdx.x;
    float part = 0.f;
    for (int k = tid; k < HID; k += 256) {
        float wv = w2[k * 128 + j];
        w2st[j * HID + k] = f2bf(s[k] * wv);
        part += grn_b[k] * wv;
    }
    #pragma unroll
    for (int m = 1; m < 64; m <<= 1) part += __shfl_xor(part, m);
    if ((tid & 63) == 0) r4[tid >> 6] = part;
    __syncthreads();
    if (tid == 0)
        bvec[j] = r4[0] + r4[1] + r4[2] + r4[3] + b2[j];
}

// ---------------------------------------------------------------------------
// GEMM2: out = y2_grn @ w2 + bvec + residual   (GRN scale folded into w2st)
// ---------------------------------------------------------------------------
__global__ __launch_bounds__(256) void gemm2_kernel(
    const ushort* __restrict__ y2,      // N x 512 bf16
    const ushort* __restrict__ w2st,    // 128 x 512 bf16 (n-major)
    const float*  __restrict__ bvec,    // 128
    const ushort* __restrict__ resid,   // N x 128 bf16
    float*        __restrict__ outf,    // N x 128 fp32 (or null)
    ushort*       __restrict__ xbfout)  // N x 128 bf16 (or null)
{
    __shared__ __align__(16) ushort sA[128 * 128];
    __shared__ __align__(16) ushort sB[128 * 128];
    const int tid = threadIdx.x;
    const int m0 = blockIdx.x << 7;

    f32x4 acc[2][8];
    #pragma unroll
    for (int rt = 0; rt < 2; ++rt)
        #pragma unroll
        for (int ct = 0; ct < 8; ++ct) { f32x4 z = {0.f,0.f,0.f,0.f}; acc[rt][ct] = z; }

    gemm_core<512>(y2, 512, w2st, 512, m0, 0, sA, sB, acc, tid);

    const int lane = tid & 63, wv = tid >> 6, lr = lane & 15, q = lane >> 4;
    float bv[8];
    #pragma unroll
    for (int ct = 0; ct < 8; ++ct) bv[ct] = bvec[(ct << 4) + lr];

    #pragma unroll
    for (int rt = 0; rt < 2; ++rt)
        #pragma unroll
        for (int r = 0; r < 4; ++r) {
            const int m = m0 + (wv << 5) + (rt << 4) + (q << 2) + r;
            const size_t base = (size_t)m * DIM;
            #pragma unroll
            for (int ct = 0; ct < 8; ++ct) {
                const int j = (ct << 4) + lr;
                float v = acc[rt][ct][r] + bv[ct] + bf2f(resid[base + j]);
                if (outf)   outf[base + j] = v;
                if (xbfout) xbfout[base + j] = f2bf(v);
            }
        }
}

// ---------------------------------------------------------------------------
extern "C" void kernel_launch(void* const* d_in, const int* in_sizes, int n_in,
                              void* d_out, int out_size, void* d_ws, size_t ws_size,
                              hipStream_t stream)
{
    const float* feats = (const float*)d_in[0];
    const float* w_dw  = (const float*)d_in[1];
    const float* b_dw  = (const float*)d_in[2];
    const float* ln_g  = (const float*)d_in[3];
    const float* ln_b  = (const float*)d_in[4];
    const float* w1    = (const float*)d_in[5];
    const float* b1    = (const float*)d_in[6];
    const float* grn_g = (const float*)d_in[7];
    const float* grn_b = (const float*)d_in[8];
    const float* w2    = (const float*)d_in[9];
    const float* b2    = (const float*)d_in[10];
    const int*   nbr   = (const int*)d_in[11];

    char* ws = (char*)d_ws;
    size_t o = 0;
    ushort* y2    = (ushort*)(ws + o); o += (size_t)NPTS * HID * 2;        // 160 MB
    ushort* y1    = (ushort*)(ws + o); o += (size_t)NPTS * DIM * 2;        //  40 MB
    ushort* xbf   = (ushort*)(ws + o); o += (size_t)NPTS * DIM * 2;        //  40 MB
    int*    wl    = (int*)   (ws + o); o += ((size_t)NPTS * 52 + 64) * 4;  //  33 MB
    int*    nrnd  = (int*)   (ws + o); o += (size_t)NPTS * 4;
    ushort* w1t   = (ushort*)(ws + o); o += (size_t)HID * DIM * 2;
    ushort* w2st  = (ushort*)(ws + o); o += (size_t)HID * DIM * 2;
    float*  sbuf  = (float*) (ws + o); o += 2048;
    float*  ssq   = (float*) (ws + o); o += 2048;
    float*  bvec  = (float*) (ws + o); o += 512;

    cast_bf16_kernel<<<NPTS * DIM / 4 / 256, 256, 0, stream>>>(feats, xbf);
    compact2_kernel<<<NPTS / 4, 256, 0, stream>>>(nbr, wl, nrnd);

    for (int l = 0; l < DEPTH; ++l) {
        const float* wdw_l = w_dw  + (size_t)l * KK2 * DIM;
        const float* bdw_l = b_dw  + (size_t)l * DIM;
        const float* lng_l = ln_g  + (size_t)l * DIM;
        const float* lnb_l = ln_b  + (size_t)l * DIM;
        const float* w1_l  = w1    + (size_t)l * DIM * HID;
        const float* b1_l  = b1    + (size_t)l * HID;
        const float* gg_l  = grn_g + (size_t)l * HID;
        const float* gb_l  = grn_b + (size_t)l * HID;
        const float* w2_l  = w2    + (size_t)l * HID * DIM;
        const float* b2_l  = b2    + (size_t)l * DIM;

        w1t_kernel<<<512, 128, 0, stream>>>(w1_l, w1t, ssq);
        dwln3_kernel<<<NPTS / 16, 1024, 0, stream>>>(
            xbf, wl, nrnd, wdw_l, bdw_l, lng_l, lnb_l, y1);
        gemm1_kernel<<<dim3(NPTS / 128, 4), 256, 0, stream>>>(y1, w1t, b1_l, y2, ssq);
        grn_prep_kernel<<<1, 512, 0, stream>>>(ssq, gg_l, sbuf);
        prep_w2_kernel<<<128, 256, 0, stream>>>(sbuf, w2_l, gb_l, b2_l, w2st, bvec);
        if (l == 0) {
            gemm2_kernel<<<NPTS / 128, 256, 0, stream>>>(
                y2, w2st, bvec, xbf, nullptr, xbf);
        } else {
            gemm2_kernel<<<NPTS / 128, 256, 0, stream>>>(
                y2, w2st, bvec, xbf, (float*)d_out, nullptr);
        }
    }
}